// Round 7
// baseline (339.342 us; speedup 1.0000x reference)
//
#include <hip/hip_runtime.h>

// GCN: 3 layers, dims 64->64->64->32, N=100000 nodes, E=1600000 edges.
// Round 17 (dispatch-count reduction, no grid.sync):
//  - Budget: kernels ~190us of 296 -> ~105us is inter-dispatch overhead
//    (~11us/boundary; matches prior session's direct gap measurement).
//    R14 proved grid.sync is not the tool (~100us/sync on 8 XCDs).
//  - 9 -> 7 dispatches:
//    (a) k_scan1 = scan_partial + scan_final in ONE kernel: every block
//        redundantly computes all chunk-sums (wave-shuffle, L2-hot), scans
//        them in LDS, then scans its own chunk.
//    (b) k_build_gemm = bucket_build + layer-1 GEMM: after csr/row_start/dis
//        for its 256-node bucket, the same block GEMMs those 256 rows
//        (dis stashed in LDS across the phase switch).
//  - CSR geometry reverted to R11 (ACHUNK 8192, 256-node buckets, nmat 76K)
//    — R16 proved geometry is a don't-care.
//  - Gather kernels byte-identical to R11/R16 (~2.9TB/s pattern ceiling).

typedef __attribute__((ext_vector_type(8))) _Float16 half8;
typedef __attribute__((ext_vector_type(4))) _Float16 half4;

static inline int cdiv(int a, int b) { return (a + b - 1) / b; }

#define ACHUNK 8192   // edges per pass-A block (256 thr x 32)
#define MAXNBK 512    // max buckets (N <= 131072)
#define SCAN_CHUNK 1024
#define BCAP 6144     // bucket capacity for LDS sort (mean 4092)

// ---- pass A1: per-block bucket histogram -> counts_t[bucket*NBA + block]
__global__ __launch_bounds__(256)
void k_bucket_hist(const int* __restrict__ dst, int* __restrict__ counts_t,
                   int NBK, int NBA, int E) {
    __shared__ int cnt[MAXNBK];
    int t = threadIdx.x, b = blockIdx.x;
    for (int i = t; i < NBK; i += 256) cnt[i] = 0;
    __syncthreads();
    int e0 = b * ACHUNK;
#pragma unroll 8
    for (int j = 0; j < ACHUNK / 256; ++j) {
        int e = e0 + j * 256 + t;
        if (e < E) atomicAdd(&cnt[dst[e] >> 8], 1);
    }
    __syncthreads();
    for (int i = t; i < NBK; i += 256) counts_t[i * NBA + b] = cnt[i];
}

// ---- fused hierarchical scan, ONE dispatch. nb <= 256 blocks.
// Phase A: every block computes all nb chunk-sums (wave w handles chunks
//          w, w+4, ...; 64-lane shuffle reduce; no block syncs).
// Phase B: LDS Hillis-Steele over chunk totals -> this block's base.
// Phase C: scan own chunk, write offsets.
__global__ __launch_bounds__(256)
void k_scan1(const int* __restrict__ a, int* __restrict__ out, int nb, int n) {
    __shared__ int ct[256];
    __shared__ int sh[256];
    int t = threadIdx.x, bk = blockIdx.x;
    int wave = t >> 6, lane = t & 63;
    // Phase A
    for (int q = wave; q < nb; q += 4) {
        int base = q * SCAN_CHUNK + lane * 16;
        int s = 0;
#pragma unroll
        for (int j = 0; j < 16; ++j) {
            int i = base + j;
            if (i < n) s += a[i];
        }
#pragma unroll
        for (int off = 32; off > 0; off >>= 1)
            s += __shfl_xor(s, off, 64);
        if (lane == 0) ct[q] = s;
    }
    __syncthreads();
    // Phase B: inclusive scan of ct[0..nb) into sh
    sh[t] = (t < nb) ? ct[t] : 0;
    __syncthreads();
    for (int off = 1; off < 256; off <<= 1) {
        int u = (t >= off) ? sh[t - off] : 0;
        __syncthreads();
        sh[t] += u;
        __syncthreads();
    }
    int bbase = (bk == 0) ? 0 : sh[bk - 1];
    __syncthreads();
    // Phase C: scan own chunk
    int base = bk * SCAN_CHUNK + t * 4;
    int v[4];
    int s = 0;
#pragma unroll
    for (int j = 0; j < 4; ++j) {
        int i = base + j;
        v[j] = (i < n) ? a[i] : 0;
        s += v[j];
    }
    sh[t] = s;
    __syncthreads();
    for (int off = 1; off < 256; off <<= 1) {
        int u = (t >= off) ? sh[t - off] : 0;
        __syncthreads();
        sh[t] += u;
        __syncthreads();
    }
    int run = sh[t] - s + bbase;
#pragma unroll
    for (int j = 0; j < 4; ++j) {
        int i = base + j;
        if (i < n) { out[i] = run; run += v[j]; }
    }
}

// ---- pass A3: scatter edges into bucket regions via LDS cursors.
// packed word: src (24 bits) | (dst & 255) << 24.
__global__ __launch_bounds__(256)
void k_bucket_scatter(const int* __restrict__ src, const int* __restrict__ dst,
                      const int* __restrict__ offsets, unsigned* __restrict__ bucketed,
                      int NBK, int NBA, int E) {
    __shared__ int curs[MAXNBK];
    int t = threadIdx.x, b = blockIdx.x;
    for (int i = t; i < NBK; i += 256) curs[i] = offsets[i * NBA + b];
    __syncthreads();
    int e0 = b * ACHUNK;
#pragma unroll 8
    for (int j = 0; j < ACHUNK / 256; ++j) {
        int e = e0 + j * 256 + t;
        if (e < E) {
            int d = dst[e];
            int pos = atomicAdd(&curs[d >> 8], 1);
            bucketed[pos] = (unsigned)src[e] | ((unsigned)(d & 255) << 24);
        }
    }
}

// ---- pass B + layer-1 GEMM, ONE kernel. Per 256-node bucket:
//  build: LDS hist -> scan -> LDS sort -> coalesced csr_src; row_start, dis.
//  gemm:  H = fp16((X @ W1) * dis[row]) for this bucket's 256 rows
//         (8 sub-tiles of 32 rows; dis carried in LDS disL).
__global__ __launch_bounds__(256)
void k_build_gemm(const unsigned* __restrict__ bucketed,
                  const int* __restrict__ offsets,
                  int* __restrict__ csr_src, int* __restrict__ row_start,
                  float* __restrict__ dis, const float* __restrict__ X,
                  const float* __restrict__ W1, _Float16* __restrict__ H,
                  int NBK, int NBA, int N, int E) {
    __shared__ __align__(16) char smem[26624];  // union: build 26.6KB / gemm 24.7KB
    __shared__ float disL[256];
    int t = threadIdx.x, k = blockIdx.x;

    // ---- build phase ----
    {
        int* cnt = (int*)smem;
        int* sc  = cnt + 256;
        int* srt = sc + 256;
        int base = offsets[k * NBA];
        int end = (k + 1 < NBK) ? offsets[(k + 1) * NBA] : E;
        cnt[t] = 0;
        __syncthreads();
        for (int i = base + t; i < end; i += 256)
            atomicAdd(&cnt[bucketed[i] >> 24], 1);
        __syncthreads();
        int c = cnt[t];
        sc[t] = c;
        __syncthreads();
        for (int off = 1; off < 256; off <<= 1) {
            int u = (t >= off) ? sc[t - off] : 0;
            __syncthreads();
            sc[t] += u;
            __syncthreads();
        }
        int excl = sc[t] - c;
        int node = k * 256 + t;
        float dn = rsqrtf(1.0f + (float)c);
        disL[t] = dn;
        if (node < N) {
            row_start[node] = base + excl;
            dis[node] = dn;
        }
        if (k == 0 && t == 0) row_start[N] = E;
        cnt[t] = excl;  // local cursor
        __syncthreads();
        int m = end - base;
        if (m <= BCAP) {
            for (int i = base + t; i < end; i += 256) {
                unsigned w = bucketed[i];
                int r = atomicAdd(&cnt[w >> 24], 1);
                srt[r] = (int)(w & 0xFFFFFFu);
            }
            __syncthreads();
            for (int idx = t; idx < m; idx += 256)
                csr_src[base + idx] = srt[idx];
        } else {
            for (int i = base + t; i < end; i += 256) {
                unsigned w = bucketed[i];
                int pos = base + atomicAdd(&cnt[w >> 24], 1);
                csr_src[pos] = (int)(w & 0xFFFFFFu);
            }
        }
        __syncthreads();
    }

    // ---- gemm phase: this bucket's 256 rows ----
    {
        float* Ws = (float*)smem;        // 64*64 f32 = 16KB
        float* Xs = Ws + 64 * 64;        // 32*65 f32 = 8.3KB (total 24.7KB)
        constexpr int K = 64, KP = 65;
        for (int idx = t; idx < K * 64 / 4; idx += 256)
            ((float4*)Ws)[idx] = ((const float4*)W1)[idx];
        int r = t / 8, c0 = (t % 8) * 8;
        for (int rt = 0; rt < 8; ++rt) {
            int row0 = k * 256 + rt * 32;
            if (row0 >= N) break;
            for (int idx = t; idx < 32 * (K / 4); idx += 256) {
                int rr = idx / (K / 4), kq = idx % (K / 4);
                int row = row0 + rr;
                float4 vv = (row < N) ? ((const float4*)X)[(size_t)row * (K / 4) + kq]
                                      : make_float4(0.f, 0.f, 0.f, 0.f);
                Xs[rr * KP + kq * 4 + 0] = vv.x;
                Xs[rr * KP + kq * 4 + 1] = vv.y;
                Xs[rr * KP + kq * 4 + 2] = vv.z;
                Xs[rr * KP + kq * 4 + 3] = vv.w;
            }
            __syncthreads();
            int row = row0 + r;
            if (row < N) {
                float4 a0 = make_float4(0.f, 0.f, 0.f, 0.f);
                float4 a1 = make_float4(0.f, 0.f, 0.f, 0.f);
#pragma unroll
                for (int kk = 0; kk < K; ++kk) {
                    float xv = Xs[r * KP + kk];
                    float4 w0 = ((const float4*)Ws)[(kk * 64 + c0) / 4];
                    float4 w1 = ((const float4*)Ws)[(kk * 64 + c0) / 4 + 1];
                    a0.x = fmaf(xv, w0.x, a0.x);
                    a0.y = fmaf(xv, w0.y, a0.y);
                    a0.z = fmaf(xv, w0.z, a0.z);
                    a0.w = fmaf(xv, w0.w, a0.w);
                    a1.x = fmaf(xv, w1.x, a1.x);
                    a1.y = fmaf(xv, w1.y, a1.y);
                    a1.z = fmaf(xv, w1.z, a1.z);
                    a1.w = fmaf(xv, w1.w, a1.w);
                }
                float dn = disL[rt * 32 + r];
                half8 hv;
                hv[0] = (_Float16)(a0.x * dn);
                hv[1] = (_Float16)(a0.y * dn);
                hv[2] = (_Float16)(a0.z * dn);
                hv[3] = (_Float16)(a0.w * dn);
                hv[4] = (_Float16)(a1.x * dn);
                hv[5] = (_Float16)(a1.y * dn);
                hv[6] = (_Float16)(a1.z * dn);
                hv[7] = (_Float16)(a1.w * dn);
                ((half8*)H)[(size_t)row * 8 + c0 / 8] = hv;
            }
            __syncthreads();
        }
    }
}

// ---- FUSED: aggregate(64) [+relu] -> LDS -> GEMM(64 x MOUT) -> h' fp16.
// 32 nodes per block (4 waves x 8 nodes, lane-per-8-features, 8-edge unroll).
// W staged as fp16 in LDS, fp32 math.
template <int MOUT>
__global__ __launch_bounds__(256, 8)
void k_fused_agg_gemm(const _Float16* __restrict__ h, const float* __restrict__ dis,
                      const int* __restrict__ row_start, const int* __restrict__ csr_src,
                      const float* __restrict__ bagg, const float* __restrict__ W,
                      _Float16* __restrict__ H, int n) {
    constexpr int K = 64, KP = K + 1;
    __shared__ __align__(16) _Float16 Ws[K * MOUT];
    __shared__ float Xs[32 * KP];
    int tid = threadIdx.x;
    for (int idx = tid; idx < K * MOUT / 4; idx += 256) {
        float4 wv = ((const float4*)W)[idx];
        half4 h4;
        h4[0] = (_Float16)wv.x;
        h4[1] = (_Float16)wv.y;
        h4[2] = (_Float16)wv.z;
        h4[3] = (_Float16)wv.w;
        ((half4*)Ws)[idx] = h4;
    }

    int wave = tid >> 6, lane = tid & 63;
    int sub = lane >> 3, fl = lane & 7;
    int node0 = blockIdx.x * 32;
    int node = node0 + wave * 8 + sub;
    if (node < n) {
        const half8* h8 = (const half8*)h;
        float acc[8];
#pragma unroll
        for (int j = 0; j < 8; ++j) acc[j] = 0.f;
        int e = row_start[node], e1 = row_start[node + 1];
        for (; e + 7 < e1; e += 8) {
            int s0 = csr_src[e], s1 = csr_src[e + 1];
            int s2 = csr_src[e + 2], s3 = csr_src[e + 3];
            int s4 = csr_src[e + 4], s5 = csr_src[e + 5];
            int s6 = csr_src[e + 6], s7 = csr_src[e + 7];
            half8 v0 = h8[(size_t)s0 * 8 + fl];
            half8 v1 = h8[(size_t)s1 * 8 + fl];
            half8 v2 = h8[(size_t)s2 * 8 + fl];
            half8 v3 = h8[(size_t)s3 * 8 + fl];
            half8 v4 = h8[(size_t)s4 * 8 + fl];
            half8 v5 = h8[(size_t)s5 * 8 + fl];
            half8 v6 = h8[(size_t)s6 * 8 + fl];
            half8 v7 = h8[(size_t)s7 * 8 + fl];
#pragma unroll
            for (int j = 0; j < 8; ++j)
                acc[j] += (((float)v0[j] + (float)v1[j]) + ((float)v2[j] + (float)v3[j])) +
                          (((float)v4[j] + (float)v5[j]) + ((float)v6[j] + (float)v7[j]));
        }
        for (; e + 3 < e1; e += 4) {
            int s0 = csr_src[e], s1 = csr_src[e + 1];
            int s2 = csr_src[e + 2], s3 = csr_src[e + 3];
            half8 v0 = h8[(size_t)s0 * 8 + fl];
            half8 v1 = h8[(size_t)s1 * 8 + fl];
            half8 v2 = h8[(size_t)s2 * 8 + fl];
            half8 v3 = h8[(size_t)s3 * 8 + fl];
#pragma unroll
            for (int j = 0; j < 8; ++j)
                acc[j] += ((float)v0[j] + (float)v1[j]) + ((float)v2[j] + (float)v3[j]);
        }
        for (; e < e1; ++e) {
            int s0 = csr_src[e];
            half8 v0 = h8[(size_t)s0 * 8 + fl];
#pragma unroll
            for (int j = 0; j < 8; ++j) acc[j] += (float)v0[j];
        }
        float dn = dis[node];
        half8 hv = h8[(size_t)node * 8 + fl];
        float4 b0 = ((const float4*)bagg)[fl * 2];
        float4 b1 = ((const float4*)bagg)[fl * 2 + 1];
        int rrow = wave * 8 + sub;
        float* xp = &Xs[rrow * KP + fl * 8];
        xp[0] = fmaxf((acc[0] + (float)hv[0]) * dn + b0.x, 0.f);
        xp[1] = fmaxf((acc[1] + (float)hv[1]) * dn + b0.y, 0.f);
        xp[2] = fmaxf((acc[2] + (float)hv[2]) * dn + b0.z, 0.f);
        xp[3] = fmaxf((acc[3] + (float)hv[3]) * dn + b0.w, 0.f);
        xp[4] = fmaxf((acc[4] + (float)hv[4]) * dn + b1.x, 0.f);
        xp[5] = fmaxf((acc[5] + (float)hv[5]) * dn + b1.y, 0.f);
        xp[6] = fmaxf((acc[6] + (float)hv[6]) * dn + b1.z, 0.f);
        xp[7] = fmaxf((acc[7] + (float)hv[7]) * dn + b1.w, 0.f);
    }
    __syncthreads();

    constexpr int TPR = 8;
    constexpr int CPT = MOUT / TPR;   // 8 (MOUT=64) or 4 (MOUT=32)
    int r = tid / TPR, c0 = (tid % TPR) * CPT;
    int row = node0 + r;
    if (row >= n) return;
    float4 a0 = make_float4(0.f, 0.f, 0.f, 0.f);
    float4 a1 = make_float4(0.f, 0.f, 0.f, 0.f);
#pragma unroll
    for (int k = 0; k < K; ++k) {
        float xv = Xs[r * KP + k];
        if constexpr (CPT == 8) {
            half8 w = ((const half8*)Ws)[(k * MOUT + c0) / 8];
            a0.x = fmaf(xv, (float)w[0], a0.x);
            a0.y = fmaf(xv, (float)w[1], a0.y);
            a0.z = fmaf(xv, (float)w[2], a0.z);
            a0.w = fmaf(xv, (float)w[3], a0.w);
            a1.x = fmaf(xv, (float)w[4], a1.x);
            a1.y = fmaf(xv, (float)w[5], a1.y);
            a1.z = fmaf(xv, (float)w[6], a1.z);
            a1.w = fmaf(xv, (float)w[7], a1.w);
        } else {
            half4 w = ((const half4*)Ws)[(k * MOUT + c0) / 4];
            a0.x = fmaf(xv, (float)w[0], a0.x);
            a0.y = fmaf(xv, (float)w[1], a0.y);
            a0.z = fmaf(xv, (float)w[2], a0.z);
            a0.w = fmaf(xv, (float)w[3], a0.w);
        }
    }
    float dn = dis[row];
    if constexpr (CPT == 8) {
        half8 hv;
        hv[0] = (_Float16)(a0.x * dn);
        hv[1] = (_Float16)(a0.y * dn);
        hv[2] = (_Float16)(a0.z * dn);
        hv[3] = (_Float16)(a0.w * dn);
        hv[4] = (_Float16)(a1.x * dn);
        hv[5] = (_Float16)(a1.y * dn);
        hv[6] = (_Float16)(a1.z * dn);
        hv[7] = (_Float16)(a1.w * dn);
        ((half8*)H)[(size_t)row * (MOUT / 8) + c0 / 8] = hv;
    } else {
        half4 hv;
        hv[0] = (_Float16)(a0.x * dn);
        hv[1] = (_Float16)(a0.y * dn);
        hv[2] = (_Float16)(a0.z * dn);
        hv[3] = (_Float16)(a0.w * dn);
        ((half4*)H)[(size_t)row * (MOUT / 4) + c0 / 4] = hv;
    }
}

// ---- final aggregate: M=32, fp32 out, no relu.
__global__ __launch_bounds__(256, 8)
void k_aggregate32(const _Float16* __restrict__ h, const float* __restrict__ dis,
                   const int* __restrict__ row_start, const int* __restrict__ csr_src,
                   const float* __restrict__ b, float* __restrict__ out, int n) {
    constexpr int LPN = 4, NPW = 16;
    int gtid = blockIdx.x * blockDim.x + threadIdx.x;
    int wave = gtid >> 6;
    int lane = threadIdx.x & 63;
    int sub = lane / LPN, fl = lane % LPN;
    int node = wave * NPW + sub;
    if (node >= n) return;
    const half8* h8 = (const half8*)h;
    float acc[8];
#pragma unroll
    for (int j = 0; j < 8; ++j) acc[j] = 0.f;
    int e = row_start[node], e1 = row_start[node + 1];
    for (; e + 7 < e1; e += 8) {
        int s0 = csr_src[e], s1 = csr_src[e + 1];
        int s2 = csr_src[e + 2], s3 = csr_src[e + 3];
        int s4 = csr_src[e + 4], s5 = csr_src[e + 5];
        int s6 = csr_src[e + 6], s7 = csr_src[e + 7];
        half8 v0 = h8[(size_t)s0 * LPN + fl];
        half8 v1 = h8[(size_t)s1 * LPN + fl];
        half8 v2 = h8[(size_t)s2 * LPN + fl];
        half8 v3 = h8[(size_t)s3 * LPN + fl];
        half8 v4 = h8[(size_t)s4 * LPN + fl];
        half8 v5 = h8[(size_t)s5 * LPN + fl];
        half8 v6 = h8[(size_t)s6 * LPN + fl];
        half8 v7 = h8[(size_t)s7 * LPN + fl];
#pragma unroll
        for (int j = 0; j < 8; ++j)
            acc[j] += (((float)v0[j] + (float)v1[j]) + ((float)v2[j] + (float)v3[j])) +
                      (((float)v4[j] + (float)v5[j]) + ((float)v6[j] + (float)v7[j]));
    }
    for (; e + 3 < e1; e += 4) {
        int s0 = csr_src[e], s1 = csr_src[e + 1];
        int s2 = csr_src[e + 2], s3 = csr_src[e + 3];
        half8 v0 = h8[(size_t)s0 * LPN + fl];
        half8 v1 = h8[(size_t)s1 * LPN + fl];
        half8 v2 = h8[(size_t)s2 * LPN + fl];
        half8 v3 = h8[(size_t)s3 * LPN + fl];
#pragma unroll
        for (int j = 0; j < 8; ++j)
            acc[j] += ((float)v0[j] + (float)v1[j]) + ((float)v2[j] + (float)v3[j]);
    }
    for (; e < e1; ++e) {
        int s0 = csr_src[e];
        half8 v0 = h8[(size_t)s0 * LPN + fl];
#pragma unroll
        for (int j = 0; j < 8; ++j) acc[j] += (float)v0[j];
    }
    float dn = dis[node];
    half8 hv = h8[(size_t)node * LPN + fl];
    float4 b0 = ((const float4*)b)[fl * 2];
    float4 b1 = ((const float4*)b)[fl * 2 + 1];
    float4* op = (float4*)(out + ((size_t)node * LPN + fl) * 8);
    op[0] = make_float4((acc[0] + (float)hv[0]) * dn + b0.x,
                        (acc[1] + (float)hv[1]) * dn + b0.y,
                        (acc[2] + (float)hv[2]) * dn + b0.z,
                        (acc[3] + (float)hv[3]) * dn + b0.w);
    op[1] = make_float4((acc[4] + (float)hv[4]) * dn + b1.x,
                        (acc[5] + (float)hv[5]) * dn + b1.y,
                        (acc[6] + (float)hv[6]) * dn + b1.z,
                        (acc[7] + (float)hv[7]) * dn + b1.w);
}

extern "C" void kernel_launch(void* const* d_in, const int* in_sizes, int n_in,
                              void* d_out, int out_size, void* d_ws, size_t ws_size,
                              hipStream_t stream) {
    const float* x   = (const float*)d_in[0];
    const int*   ei  = (const int*)d_in[1];
    const float* W1  = (const float*)d_in[2];
    const float* b1  = (const float*)d_in[3];
    const float* W2  = (const float*)d_in[4];
    const float* b2  = (const float*)d_in[5];
    const float* W3  = (const float*)d_in[6];
    const float* b3  = (const float*)d_in[7];
    float* out = (float*)d_out;

    const int N = in_sizes[0] / 64;
    const int E = in_sizes[1] / 2;
    const int* src = ei;
    const int* dst = ei + E;

    const int NBK = cdiv(N, 256);           // 391 buckets of 256 nodes
    const int NBA = cdiv(E, ACHUNK);        // 196 chunks
    const int nmat = NBK * NBA;             // 76636 scan elements
    const int nb = cdiv(nmat, SCAN_CHUNK);  // 75 <= 256

    // workspace layout
    const size_t Np = (size_t)((N + 63) / 64) * 64;
    char* p = (char*)d_ws;
    int*      counts_t = (int*)p;      p += (size_t)nmat * sizeof(int);
    int*      offsets  = (int*)p;      p += (size_t)nmat * sizeof(int);
    int*      row_start= (int*)p;      p += (Np + 64) * sizeof(int);
    float*    dis      = (float*)p;    p += Np * sizeof(float);
    unsigned* bucketed = (unsigned*)p; p += (size_t)E * sizeof(unsigned);
    int*      csr_src  = (int*)p;      p += (size_t)E * sizeof(int);
    _Float16* bufA     = (_Float16*)p; p += Np * 64 * sizeof(_Float16);
    _Float16* bufB     = (_Float16*)p; p += Np * 64 * sizeof(_Float16);
    (void)ws_size;

    const int B = 256;

    // ---- CSR build + layer-1 gemm: 4 dispatches ----
    k_bucket_hist<<<NBA, B, 0, stream>>>(dst, counts_t, NBK, NBA, E);
    k_scan1<<<nb, B, 0, stream>>>(counts_t, offsets, nb, nmat);
    k_bucket_scatter<<<NBA, B, 0, stream>>>(src, dst, offsets, bucketed, NBK, NBA, E);
    k_build_gemm<<<NBK, B, 0, stream>>>(bucketed, offsets, csr_src, row_start, dis,
                                        x, W1, bufA, NBK, NBA, N, E);

    // ---- fused: agg(h1)+relu -> gemm W2 -> h2 (bufB) ----
    k_fused_agg_gemm<64><<<cdiv(N, 32), B, 0, stream>>>(
        bufA, dis, row_start, csr_src, b1, W2, bufB, N);
    // ---- fused: agg(h2)+relu -> gemm W3 -> h3 (bufA, 32-dim) ----
    k_fused_agg_gemm<32><<<cdiv(N, 32), B, 0, stream>>>(
        bufB, dis, row_start, csr_src, b2, W3, bufA, N);
    // ---- final aggregate: agg(h3) + b3 -> out (fp32) ----
    k_aggregate32<<<cdiv(cdiv(N, 16) * 64, B), B, 0, stream>>>(
        bufA, dis, row_start, csr_src, b3, out, N);
}

// Round 8
// 333.327 us; speedup vs baseline: 1.0180x; 1.0180x over previous
//
#include <hip/hip_runtime.h>

// GCN: 3 layers, dims 64->64->64->32, N=100000 nodes, E=1600000 edges.
// Round 18 (isolate R17's merges: keep scan1, revert build_gemm):
//  - R17 (+43us): k_build_gemm redistributed layer-1 GEMM from 3125 blocks
//    onto build's 391 blocks (1.5/CU, 8 serial subtiles) -> latency-bound.
//    Lesson: kernel merges need compatible grid shapes.
//  - Keep k_scan1 (2 scans -> 1 dispatch; redundant chunk-sum phase is ~3us,
//    L2-hot). Revert bucket_build and gemm_f to separate proven dispatches.
//  - 8 dispatches total. Gather kernels byte-identical to R11/R16
//    (~2.9TB/s random-gather service ceiling, invariant across 6 variants).

typedef __attribute__((ext_vector_type(8))) _Float16 half8;
typedef __attribute__((ext_vector_type(4))) _Float16 half4;

static inline int cdiv(int a, int b) { return (a + b - 1) / b; }

#define ACHUNK 8192   // edges per pass-A block (256 thr x 32)
#define MAXNBK 512    // max buckets (N <= 131072)
#define SCAN_CHUNK 1024
#define BCAP 6144     // bucket capacity for LDS sort (mean 4092)

// ---- pass A1: per-block bucket histogram -> counts_t[bucket*NBA + block]
__global__ __launch_bounds__(256)
void k_bucket_hist(const int* __restrict__ dst, int* __restrict__ counts_t,
                   int NBK, int NBA, int E) {
    __shared__ int cnt[MAXNBK];
    int t = threadIdx.x, b = blockIdx.x;
    for (int i = t; i < NBK; i += 256) cnt[i] = 0;
    __syncthreads();
    int e0 = b * ACHUNK;
#pragma unroll 8
    for (int j = 0; j < ACHUNK / 256; ++j) {
        int e = e0 + j * 256 + t;
        if (e < E) atomicAdd(&cnt[dst[e] >> 8], 1);
    }
    __syncthreads();
    for (int i = t; i < NBK; i += 256) counts_t[i * NBA + b] = cnt[i];
}

// ---- fused hierarchical scan, ONE dispatch. nb <= 256 blocks.
// Phase A: every block computes all nb chunk-sums (wave w handles chunks
//          w, w+4, ...; 64-lane shuffle reduce; no block syncs needed).
// Phase B: LDS Hillis-Steele over chunk totals -> this block's base.
// Phase C: scan own chunk, write offsets.
__global__ __launch_bounds__(256)
void k_scan1(const int* __restrict__ a, int* __restrict__ out, int nb, int n) {
    __shared__ int ct[256];
    __shared__ int sh[256];
    int t = threadIdx.x, bk = blockIdx.x;
    int wave = t >> 6, lane = t & 63;
    // Phase A
    for (int q = wave; q < nb; q += 4) {
        int base = q * SCAN_CHUNK + lane * 16;
        int s = 0;
#pragma unroll
        for (int j = 0; j < 16; ++j) {
            int i = base + j;
            if (i < n) s += a[i];
        }
#pragma unroll
        for (int off = 32; off > 0; off >>= 1)
            s += __shfl_xor(s, off, 64);
        if (lane == 0) ct[q] = s;
    }
    __syncthreads();
    // Phase B: inclusive scan of ct[0..nb) into sh
    sh[t] = (t < nb) ? ct[t] : 0;
    __syncthreads();
    for (int off = 1; off < 256; off <<= 1) {
        int u = (t >= off) ? sh[t - off] : 0;
        __syncthreads();
        sh[t] += u;
        __syncthreads();
    }
    int bbase = (bk == 0) ? 0 : sh[bk - 1];
    __syncthreads();
    // Phase C: scan own chunk
    int base = bk * SCAN_CHUNK + t * 4;
    int v[4];
    int s = 0;
#pragma unroll
    for (int j = 0; j < 4; ++j) {
        int i = base + j;
        v[j] = (i < n) ? a[i] : 0;
        s += v[j];
    }
    sh[t] = s;
    __syncthreads();
    for (int off = 1; off < 256; off <<= 1) {
        int u = (t >= off) ? sh[t - off] : 0;
        __syncthreads();
        sh[t] += u;
        __syncthreads();
    }
    int run = sh[t] - s + bbase;
#pragma unroll
    for (int j = 0; j < 4; ++j) {
        int i = base + j;
        if (i < n) { out[i] = run; run += v[j]; }
    }
}

// ---- pass A3: scatter edges into bucket regions via LDS cursors.
// packed word: src (24 bits) | (dst & 255) << 24.
__global__ __launch_bounds__(256)
void k_bucket_scatter(const int* __restrict__ src, const int* __restrict__ dst,
                      const int* __restrict__ offsets, unsigned* __restrict__ bucketed,
                      int NBK, int NBA, int E) {
    __shared__ int curs[MAXNBK];
    int t = threadIdx.x, b = blockIdx.x;
    for (int i = t; i < NBK; i += 256) curs[i] = offsets[i * NBA + b];
    __syncthreads();
    int e0 = b * ACHUNK;
#pragma unroll 8
    for (int j = 0; j < ACHUNK / 256; ++j) {
        int e = e0 + j * 256 + t;
        if (e < E) {
            int d = dst[e];
            int pos = atomicAdd(&curs[d >> 8], 1);
            bucketed[pos] = (unsigned)src[e] | ((unsigned)(d & 255) << 24);
        }
    }
}

// ---- pass B: one block per 256-node bucket. LDS hist -> scan -> LDS sort ->
// coalesced csr_src write; row_start, dis.
__global__ __launch_bounds__(256)
void k_bucket_build(const unsigned* __restrict__ bucketed,
                    const int* __restrict__ offsets,
                    int* __restrict__ csr_src, int* __restrict__ row_start,
                    float* __restrict__ dis, int NBK, int NBA, int N, int E) {
    __shared__ int cnt[256];
    __shared__ int sc[256];
    __shared__ int srt[BCAP];
    int t = threadIdx.x, k = blockIdx.x;
    int base = offsets[k * NBA];
    int end = (k + 1 < NBK) ? offsets[(k + 1) * NBA] : E;
    cnt[t] = 0;
    __syncthreads();
    for (int i = base + t; i < end; i += 256)
        atomicAdd(&cnt[bucketed[i] >> 24], 1);
    __syncthreads();
    int c = cnt[t];
    sc[t] = c;
    __syncthreads();
    for (int off = 1; off < 256; off <<= 1) {
        int u = (t >= off) ? sc[t - off] : 0;
        __syncthreads();
        sc[t] += u;
        __syncthreads();
    }
    int excl = sc[t] - c;
    int node = k * 256 + t;
    if (node < N) {
        row_start[node] = base + excl;
        dis[node] = rsqrtf(1.0f + (float)c);
    }
    if (k == 0 && t == 0) row_start[N] = E;
    cnt[t] = excl;  // local cursor
    __syncthreads();
    int m = end - base;
    if (m <= BCAP) {
        for (int i = base + t; i < end; i += 256) {
            unsigned w = bucketed[i];
            int r = atomicAdd(&cnt[w >> 24], 1);
            srt[r] = (int)(w & 0xFFFFFFu);
        }
        __syncthreads();
        for (int idx = t; idx < m; idx += 256)
            csr_src[base + idx] = srt[idx];
    } else {
        // fallback: scattered writes (statistically unreachable)
        for (int i = base + t; i < end; i += 256) {
            unsigned w = bucketed[i];
            int pos = base + atomicAdd(&cnt[w >> 24], 1);
            csr_src[pos] = (int)(w & 0xFFFFFFu);
        }
    }
}

// ---- fp32-input GEMM (layer 1): H = fp16((X@W) * dis[row]), 8 outs/thread
template <int K, int M>
__global__ void k_gemm_f(const float* __restrict__ X, const float* __restrict__ W,
                         const float* __restrict__ dis, _Float16* __restrict__ H, int n) {
    constexpr int TPR = M / 8;
    constexpr int ROWS = 256 / TPR;
    constexpr int KP = K + 1;
    __shared__ float Ws[K * M];
    __shared__ float Xs[ROWS * KP];
    int tid = threadIdx.x;
    for (int idx = tid; idx < K * M / 4; idx += 256)
        ((float4*)Ws)[idx] = ((const float4*)W)[idx];
    int row0 = blockIdx.x * ROWS;
    for (int idx = tid; idx < ROWS * (K / 4); idx += 256) {
        int r = idx / (K / 4), kq = idx % (K / 4);
        int row = row0 + r;
        float4 vv = (row < n) ? ((const float4*)X)[(size_t)row * (K / 4) + kq]
                              : make_float4(0.f, 0.f, 0.f, 0.f);
        Xs[r * KP + kq * 4 + 0] = vv.x;
        Xs[r * KP + kq * 4 + 1] = vv.y;
        Xs[r * KP + kq * 4 + 2] = vv.z;
        Xs[r * KP + kq * 4 + 3] = vv.w;
    }
    __syncthreads();
    int r = tid / TPR, c0 = (tid % TPR) * 8;
    int row = row0 + r;
    if (row >= n) return;
    float4 a0 = make_float4(0.f, 0.f, 0.f, 0.f);
    float4 a1 = make_float4(0.f, 0.f, 0.f, 0.f);
#pragma unroll
    for (int k = 0; k < K; ++k) {
        float xv = Xs[r * KP + k];
        float4 w0 = ((const float4*)Ws)[(k * M + c0) / 4];
        float4 w1 = ((const float4*)Ws)[(k * M + c0) / 4 + 1];
        a0.x = fmaf(xv, w0.x, a0.x);
        a0.y = fmaf(xv, w0.y, a0.y);
        a0.z = fmaf(xv, w0.z, a0.z);
        a0.w = fmaf(xv, w0.w, a0.w);
        a1.x = fmaf(xv, w1.x, a1.x);
        a1.y = fmaf(xv, w1.y, a1.y);
        a1.z = fmaf(xv, w1.z, a1.z);
        a1.w = fmaf(xv, w1.w, a1.w);
    }
    float dn = dis[row];
    half8 hv;
    hv[0] = (_Float16)(a0.x * dn);
    hv[1] = (_Float16)(a0.y * dn);
    hv[2] = (_Float16)(a0.z * dn);
    hv[3] = (_Float16)(a0.w * dn);
    hv[4] = (_Float16)(a1.x * dn);
    hv[5] = (_Float16)(a1.y * dn);
    hv[6] = (_Float16)(a1.z * dn);
    hv[7] = (_Float16)(a1.w * dn);
    ((half8*)H)[(size_t)row * (M / 8) + c0 / 8] = hv;
}

// ---- FUSED: aggregate(64) [+relu] -> LDS -> GEMM(64 x MOUT) -> h' fp16.
// 32 nodes per block (4 waves x 8 nodes, lane-per-8-features, 8-edge unroll).
// W staged as fp16 in LDS, fp32 math.
template <int MOUT>
__global__ __launch_bounds__(256, 8)
void k_fused_agg_gemm(const _Float16* __restrict__ h, const float* __restrict__ dis,
                      const int* __restrict__ row_start, const int* __restrict__ csr_src,
                      const float* __restrict__ bagg, const float* __restrict__ W,
                      _Float16* __restrict__ H, int n) {
    constexpr int K = 64, KP = K + 1;
    __shared__ __align__(16) _Float16 Ws[K * MOUT];
    __shared__ float Xs[32 * KP];
    int tid = threadIdx.x;
    for (int idx = tid; idx < K * MOUT / 4; idx += 256) {
        float4 wv = ((const float4*)W)[idx];
        half4 h4;
        h4[0] = (_Float16)wv.x;
        h4[1] = (_Float16)wv.y;
        h4[2] = (_Float16)wv.z;
        h4[3] = (_Float16)wv.w;
        ((half4*)Ws)[idx] = h4;
    }

    int wave = tid >> 6, lane = tid & 63;
    int sub = lane >> 3, fl = lane & 7;
    int node0 = blockIdx.x * 32;
    int node = node0 + wave * 8 + sub;
    if (node < n) {
        const half8* h8 = (const half8*)h;
        float acc[8];
#pragma unroll
        for (int j = 0; j < 8; ++j) acc[j] = 0.f;
        int e = row_start[node], e1 = row_start[node + 1];
        for (; e + 7 < e1; e += 8) {
            int s0 = csr_src[e], s1 = csr_src[e + 1];
            int s2 = csr_src[e + 2], s3 = csr_src[e + 3];
            int s4 = csr_src[e + 4], s5 = csr_src[e + 5];
            int s6 = csr_src[e + 6], s7 = csr_src[e + 7];
            half8 v0 = h8[(size_t)s0 * 8 + fl];
            half8 v1 = h8[(size_t)s1 * 8 + fl];
            half8 v2 = h8[(size_t)s2 * 8 + fl];
            half8 v3 = h8[(size_t)s3 * 8 + fl];
            half8 v4 = h8[(size_t)s4 * 8 + fl];
            half8 v5 = h8[(size_t)s5 * 8 + fl];
            half8 v6 = h8[(size_t)s6 * 8 + fl];
            half8 v7 = h8[(size_t)s7 * 8 + fl];
#pragma unroll
            for (int j = 0; j < 8; ++j)
                acc[j] += (((float)v0[j] + (float)v1[j]) + ((float)v2[j] + (float)v3[j])) +
                          (((float)v4[j] + (float)v5[j]) + ((float)v6[j] + (float)v7[j]));
        }
        for (; e + 3 < e1; e += 4) {
            int s0 = csr_src[e], s1 = csr_src[e + 1];
            int s2 = csr_src[e + 2], s3 = csr_src[e + 3];
            half8 v0 = h8[(size_t)s0 * 8 + fl];
            half8 v1 = h8[(size_t)s1 * 8 + fl];
            half8 v2 = h8[(size_t)s2 * 8 + fl];
            half8 v3 = h8[(size_t)s3 * 8 + fl];
#pragma unroll
            for (int j = 0; j < 8; ++j)
                acc[j] += ((float)v0[j] + (float)v1[j]) + ((float)v2[j] + (float)v3[j]);
        }
        for (; e < e1; ++e) {
            int s0 = csr_src[e];
            half8 v0 = h8[(size_t)s0 * 8 + fl];
#pragma unroll
            for (int j = 0; j < 8; ++j) acc[j] += (float)v0[j];
        }
        float dn = dis[node];
        half8 hv = h8[(size_t)node * 8 + fl];
        float4 b0 = ((const float4*)bagg)[fl * 2];
        float4 b1 = ((const float4*)bagg)[fl * 2 + 1];
        int rrow = wave * 8 + sub;
        float* xp = &Xs[rrow * KP + fl * 8];
        xp[0] = fmaxf((acc[0] + (float)hv[0]) * dn + b0.x, 0.f);
        xp[1] = fmaxf((acc[1] + (float)hv[1]) * dn + b0.y, 0.f);
        xp[2] = fmaxf((acc[2] + (float)hv[2]) * dn + b0.z, 0.f);
        xp[3] = fmaxf((acc[3] + (float)hv[3]) * dn + b0.w, 0.f);
        xp[4] = fmaxf((acc[4] + (float)hv[4]) * dn + b1.x, 0.f);
        xp[5] = fmaxf((acc[5] + (float)hv[5]) * dn + b1.y, 0.f);
        xp[6] = fmaxf((acc[6] + (float)hv[6]) * dn + b1.z, 0.f);
        xp[7] = fmaxf((acc[7] + (float)hv[7]) * dn + b1.w, 0.f);
    }
    __syncthreads();

    constexpr int TPR = 8;
    constexpr int CPT = MOUT / TPR;   // 8 (MOUT=64) or 4 (MOUT=32)
    int r = tid / TPR, c0 = (tid % TPR) * CPT;
    int row = node0 + r;
    if (row >= n) return;
    float4 a0 = make_float4(0.f, 0.f, 0.f, 0.f);
    float4 a1 = make_float4(0.f, 0.f, 0.f, 0.f);
#pragma unroll
    for (int k = 0; k < K; ++k) {
        float xv = Xs[r * KP + k];
        if constexpr (CPT == 8) {
            half8 w = ((const half8*)Ws)[(k * MOUT + c0) / 8];
            a0.x = fmaf(xv, (float)w[0], a0.x);
            a0.y = fmaf(xv, (float)w[1], a0.y);
            a0.z = fmaf(xv, (float)w[2], a0.z);
            a0.w = fmaf(xv, (float)w[3], a0.w);
            a1.x = fmaf(xv, (float)w[4], a1.x);
            a1.y = fmaf(xv, (float)w[5], a1.y);
            a1.z = fmaf(xv, (float)w[6], a1.z);
            a1.w = fmaf(xv, (float)w[7], a1.w);
        } else {
            half4 w = ((const half4*)Ws)[(k * MOUT + c0) / 4];
            a0.x = fmaf(xv, (float)w[0], a0.x);
            a0.y = fmaf(xv, (float)w[1], a0.y);
            a0.z = fmaf(xv, (float)w[2], a0.z);
            a0.w = fmaf(xv, (float)w[3], a0.w);
        }
    }
    float dn = dis[row];
    if constexpr (CPT == 8) {
        half8 hv;
        hv[0] = (_Float16)(a0.x * dn);
        hv[1] = (_Float16)(a0.y * dn);
        hv[2] = (_Float16)(a0.z * dn);
        hv[3] = (_Float16)(a0.w * dn);
        hv[4] = (_Float16)(a1.x * dn);
        hv[5] = (_Float16)(a1.y * dn);
        hv[6] = (_Float16)(a1.z * dn);
        hv[7] = (_Float16)(a1.w * dn);
        ((half8*)H)[(size_t)row * (MOUT / 8) + c0 / 8] = hv;
    } else {
        half4 hv;
        hv[0] = (_Float16)(a0.x * dn);
        hv[1] = (_Float16)(a0.y * dn);
        hv[2] = (_Float16)(a0.z * dn);
        hv[3] = (_Float16)(a0.w * dn);
        ((half4*)H)[(size_t)row * (MOUT / 4) + c0 / 4] = hv;
    }
}

// ---- final aggregate: M=32, fp32 out, no relu.
__global__ __launch_bounds__(256, 8)
void k_aggregate32(const _Float16* __restrict__ h, const float* __restrict__ dis,
                   const int* __restrict__ row_start, const int* __restrict__ csr_src,
                   const float* __restrict__ b, float* __restrict__ out, int n) {
    constexpr int LPN = 4, NPW = 16;
    int gtid = blockIdx.x * blockDim.x + threadIdx.x;
    int wave = gtid >> 6;
    int lane = threadIdx.x & 63;
    int sub = lane / LPN, fl = lane % LPN;
    int node = wave * NPW + sub;
    if (node >= n) return;
    const half8* h8 = (const half8*)h;
    float acc[8];
#pragma unroll
    for (int j = 0; j < 8; ++j) acc[j] = 0.f;
    int e = row_start[node], e1 = row_start[node + 1];
    for (; e + 7 < e1; e += 8) {
        int s0 = csr_src[e], s1 = csr_src[e + 1];
        int s2 = csr_src[e + 2], s3 = csr_src[e + 3];
        int s4 = csr_src[e + 4], s5 = csr_src[e + 5];
        int s6 = csr_src[e + 6], s7 = csr_src[e + 7];
        half8 v0 = h8[(size_t)s0 * LPN + fl];
        half8 v1 = h8[(size_t)s1 * LPN + fl];
        half8 v2 = h8[(size_t)s2 * LPN + fl];
        half8 v3 = h8[(size_t)s3 * LPN + fl];
        half8 v4 = h8[(size_t)s4 * LPN + fl];
        half8 v5 = h8[(size_t)s5 * LPN + fl];
        half8 v6 = h8[(size_t)s6 * LPN + fl];
        half8 v7 = h8[(size_t)s7 * LPN + fl];
#pragma unroll
        for (int j = 0; j < 8; ++j)
            acc[j] += (((float)v0[j] + (float)v1[j]) + ((float)v2[j] + (float)v3[j])) +
                      (((float)v4[j] + (float)v5[j]) + ((float)v6[j] + (float)v7[j]));
    }
    for (; e + 3 < e1; e += 4) {
        int s0 = csr_src[e], s1 = csr_src[e + 1];
        int s2 = csr_src[e + 2], s3 = csr_src[e + 3];
        half8 v0 = h8[(size_t)s0 * LPN + fl];
        half8 v1 = h8[(size_t)s1 * LPN + fl];
        half8 v2 = h8[(size_t)s2 * LPN + fl];
        half8 v3 = h8[(size_t)s3 * LPN + fl];
#pragma unroll
        for (int j = 0; j < 8; ++j)
            acc[j] += ((float)v0[j] + (float)v1[j]) + ((float)v2[j] + (float)v3[j]);
    }
    for (; e < e1; ++e) {
        int s0 = csr_src[e];
        half8 v0 = h8[(size_t)s0 * LPN + fl];
#pragma unroll
        for (int j = 0; j < 8; ++j) acc[j] += (float)v0[j];
    }
    float dn = dis[node];
    half8 hv = h8[(size_t)node * LPN + fl];
    float4 b0 = ((const float4*)b)[fl * 2];
    float4 b1 = ((const float4*)b)[fl * 2 + 1];
    float4* op = (float4*)(out + ((size_t)node * LPN + fl) * 8);
    op[0] = make_float4((acc[0] + (float)hv[0]) * dn + b0.x,
                        (acc[1] + (float)hv[1]) * dn + b0.y,
                        (acc[2] + (float)hv[2]) * dn + b0.z,
                        (acc[3] + (float)hv[3]) * dn + b0.w);
    op[1] = make_float4((acc[4] + (float)hv[4]) * dn + b1.x,
                        (acc[5] + (float)hv[5]) * dn + b1.y,
                        (acc[6] + (float)hv[6]) * dn + b1.z,
                        (acc[7] + (float)hv[7]) * dn + b1.w);
}

extern "C" void kernel_launch(void* const* d_in, const int* in_sizes, int n_in,
                              void* d_out, int out_size, void* d_ws, size_t ws_size,
                              hipStream_t stream) {
    const float* x   = (const float*)d_in[0];
    const int*   ei  = (const int*)d_in[1];
    const float* W1  = (const float*)d_in[2];
    const float* b1  = (const float*)d_in[3];
    const float* W2  = (const float*)d_in[4];
    const float* b2  = (const float*)d_in[5];
    const float* W3  = (const float*)d_in[6];
    const float* b3  = (const float*)d_in[7];
    float* out = (float*)d_out;

    const int N = in_sizes[0] / 64;
    const int E = in_sizes[1] / 2;
    const int* src = ei;
    const int* dst = ei + E;

    const int NBK = cdiv(N, 256);           // 391 buckets of 256 nodes
    const int NBA = cdiv(E, ACHUNK);        // 196 chunks
    const int nmat = NBK * NBA;             // 76636 scan elements
    const int nb = cdiv(nmat, SCAN_CHUNK);  // 75 <= 256

    // workspace layout
    const size_t Np = (size_t)((N + 63) / 64) * 64;
    char* p = (char*)d_ws;
    int*      counts_t = (int*)p;      p += (size_t)nmat * sizeof(int);
    int*      offsets  = (int*)p;      p += (size_t)nmat * sizeof(int);
    int*      row_start= (int*)p;      p += (Np + 64) * sizeof(int);
    float*    dis      = (float*)p;    p += Np * sizeof(float);
    unsigned* bucketed = (unsigned*)p; p += (size_t)E * sizeof(unsigned);
    int*      csr_src  = (int*)p;      p += (size_t)E * sizeof(int);
    _Float16* bufA     = (_Float16*)p; p += Np * 64 * sizeof(_Float16);
    _Float16* bufB     = (_Float16*)p; p += Np * 64 * sizeof(_Float16);
    (void)ws_size;

    const int B = 256;

    // ---- CSR build: 4 dispatches ----
    k_bucket_hist<<<NBA, B, 0, stream>>>(dst, counts_t, NBK, NBA, E);
    k_scan1<<<nb, B, 0, stream>>>(counts_t, offsets, nb, nmat);
    k_bucket_scatter<<<NBA, B, 0, stream>>>(src, dst, offsets, bucketed, NBK, NBA, E);
    k_bucket_build<<<NBK, B, 0, stream>>>(bucketed, offsets, csr_src, row_start, dis,
                                          NBK, NBA, N, E);

    // ---- layer 1 gemm: x(64) @ W1 -> h1 (bufA) ----
    k_gemm_f<64, 64><<<cdiv(N, 32), B, 0, stream>>>(x, W1, dis, bufA, N);
    // ---- fused: agg(h1)+relu -> gemm W2 -> h2 (bufB) ----
    k_fused_agg_gemm<64><<<cdiv(N, 32), B, 0, stream>>>(
        bufA, dis, row_start, csr_src, b1, W2, bufB, N);
    // ---- fused: agg(h2)+relu -> gemm W3 -> h3 (bufA, 32-dim) ----
    k_fused_agg_gemm<32><<<cdiv(N, 32), B, 0, stream>>>(
        bufB, dis, row_start, csr_src, b2, W3, bufA, N);
    // ---- final aggregate: agg(h3) + b3 -> out (fp32) ----
    k_aggregate32<<<cdiv(cdiv(N, 16) * 64, B), B, 0, stream>>>(
        bufA, dis, row_start, csr_src, b3, out, N);
}

// Round 9
// 297.267 us; speedup vs baseline: 1.1415x; 1.1213x over previous
//
#include <hip/hip_runtime.h>

// GCN: 3 layers, dims 64->64->64->32, N=100000 nodes, E=1600000 edges.
// Round 19: byte-exact revert to R16 (best measured: 296.2us).
//  - R18 isolated k_scan1 as a ~+35us regression (75 blocks = 0.3/CU, phase-A
//    stride-16 uncoalesced redundant reads). Two-scan pipeline restored.
//  - Search summary (R11-R18): traffic shaping, nt-hints, occupancy/geometry,
//    coop grid.sync (~100us/sync), global atomic scatter (140us), and two
//    kernel merges all null-or-negative. Plateau 296-302us across 7 variants.
//  - Gather kernels pinned at ~2.9TB/s random-gather service rate (FETCH
//    160MB ~= 1.15x the 8-XCD compulsory floor). Structural floor:
//    3 serial gather passes + CSR build + ~8 dispatch boundaries.

typedef __attribute__((ext_vector_type(8))) _Float16 half8;
typedef __attribute__((ext_vector_type(4))) _Float16 half4;

static inline int cdiv(int a, int b) { return (a + b - 1) / b; }

#define ACHUNK 2048   // edges per pass-A block (256 thr x 8)
#define BSHIFT 7      // 128-node buckets
#define BMASK 127
#define MAXNBK 1024   // max buckets (N <= 131072)
#define SCAN_CHUNK 1024
#define BCAP 4096     // bucket capacity for LDS sort (mean 2046)

// ---- pass A1: per-block bucket histogram -> counts_t[bucket*NBA + block]
__global__ __launch_bounds__(256)
void k_bucket_hist(const int* __restrict__ dst, int* __restrict__ counts_t,
                   int NBK, int NBA, int E) {
    __shared__ int cnt[MAXNBK];
    int t = threadIdx.x, b = blockIdx.x;
    for (int i = t; i < NBK; i += 256) cnt[i] = 0;
    __syncthreads();
    int e0 = b * ACHUNK;
#pragma unroll 8
    for (int j = 0; j < ACHUNK / 256; ++j) {
        int e = e0 + j * 256 + t;
        if (e < E) atomicAdd(&cnt[dst[e] >> BSHIFT], 1);
    }
    __syncthreads();
    for (int i = t; i < NBK; i += 256) counts_t[i * NBA + b] = cnt[i];
}

// ---- scan partial: per-block sums of SCAN_CHUNK elements
__global__ __launch_bounds__(256)
void k_scan_partial(const int* __restrict__ a, int* __restrict__ bsum, int n) {
    __shared__ int red[256];
    int t = threadIdx.x, b = blockIdx.x;
    int base = b * SCAN_CHUNK + t * 4;
    int s = 0;
#pragma unroll
    for (int j = 0; j < 4; ++j) { int i = base + j; if (i < n) s += a[i]; }
    red[t] = s;
    __syncthreads();
    for (int off = 128; off > 0; off >>= 1) {
        if (t < off) red[t] += red[t + off];
        __syncthreads();
    }
    if (t == 0) bsum[b] = red[0];
}

// ---- scan final: nb <= 1024. Each thread owns bsum[4t..4t+4); block base is
// broadcast via LDS; then standard chunk scan.
__global__ __launch_bounds__(256)
void k_scan_final(const int* __restrict__ a, const int* __restrict__ bsum,
                  int* __restrict__ out, int nb, int n) {
    __shared__ int sh[256];
    __shared__ int bb;
    int t = threadIdx.x, bk = blockIdx.x;
    // block-sum prefix over up to 1024 entries
    int bv[4];
    int bt = 0;
#pragma unroll
    for (int j = 0; j < 4; ++j) {
        int i = 4 * t + j;
        bv[j] = (i < nb) ? bsum[i] : 0;
        bt += bv[j];
    }
    sh[t] = bt;
    __syncthreads();
    for (int off = 1; off < 256; off <<= 1) {
        int u = (t >= off) ? sh[t - off] : 0;
        __syncthreads();
        sh[t] += u;
        __syncthreads();
    }
    int bexcl = sh[t] - bt;
    if (bk == 0) {
        if (t == 0) bb = 0;
    } else {
        int q = bk - 1;
        if (t == (q >> 2)) {
            int s = bexcl;
#pragma unroll
            for (int j = 0; j < 4; ++j)
                if (j <= (q & 3)) s += bv[j];
            bb = s;
        }
    }
    __syncthreads();
    int bbase = bb;
    __syncthreads();
    // chunk scan
    int base = bk * SCAN_CHUNK + t * 4;
    int v[4];
    int s = 0;
#pragma unroll
    for (int j = 0; j < 4; ++j) {
        int i = base + j;
        v[j] = (i < n) ? a[i] : 0;
        s += v[j];
    }
    sh[t] = s;
    __syncthreads();
    for (int off = 1; off < 256; off <<= 1) {
        int u = (t >= off) ? sh[t - off] : 0;
        __syncthreads();
        sh[t] += u;
        __syncthreads();
    }
    int run = sh[t] - s + bbase;
#pragma unroll
    for (int j = 0; j < 4; ++j) {
        int i = base + j;
        if (i < n) { out[i] = run; run += v[j]; }
    }
}

// ---- pass A3: scatter edges into bucket regions via LDS cursors.
// packed word: src (24 bits) | (dst & 127) << 24.
__global__ __launch_bounds__(256)
void k_bucket_scatter(const int* __restrict__ src, const int* __restrict__ dst,
                      const int* __restrict__ offsets, unsigned* __restrict__ bucketed,
                      int NBK, int NBA, int E) {
    __shared__ int curs[MAXNBK];
    int t = threadIdx.x, b = blockIdx.x;
    for (int i = t; i < NBK; i += 256) curs[i] = offsets[i * NBA + b];
    __syncthreads();
    int e0 = b * ACHUNK;
#pragma unroll 8
    for (int j = 0; j < ACHUNK / 256; ++j) {
        int e = e0 + j * 256 + t;
        if (e < E) {
            int d = dst[e];
            int pos = atomicAdd(&curs[d >> BSHIFT], 1);
            bucketed[pos] = (unsigned)src[e] | ((unsigned)(d & BMASK) << 24);
        }
    }
}

// ---- pass B: one block per 128-node bucket. LDS hist -> scan -> LDS sort ->
// coalesced csr_src write; row_start, dis.
__global__ __launch_bounds__(256)
void k_bucket_build(const unsigned* __restrict__ bucketed,
                    const int* __restrict__ offsets,
                    int* __restrict__ csr_src, int* __restrict__ row_start,
                    float* __restrict__ dis, int NBK, int NBA, int N, int E) {
    __shared__ int cnt[128];
    __shared__ int sc[128];
    __shared__ int srt[BCAP];
    int t = threadIdx.x, k = blockIdx.x;
    int base = offsets[k * NBA];
    int end = (k + 1 < NBK) ? offsets[(k + 1) * NBA] : E;
    if (t < 128) cnt[t] = 0;
    __syncthreads();
    for (int i = base + t; i < end; i += 256)
        atomicAdd(&cnt[bucketed[i] >> 24], 1);
    __syncthreads();
    int c = 0;
    if (t < 128) { c = cnt[t]; sc[t] = c; }
    __syncthreads();
    for (int off = 1; off < 128; off <<= 1) {
        int u = (t >= off && t < 128) ? sc[t - off] : 0;
        __syncthreads();
        if (t < 128) sc[t] += u;
        __syncthreads();
    }
    if (t < 128) {
        int excl = sc[t] - c;
        int node = (k << BSHIFT) + t;
        if (node < N) {
            row_start[node] = base + excl;
            dis[node] = rsqrtf(1.0f + (float)c);
        }
        cnt[t] = excl;  // local cursor
    }
    if (k == 0 && t == 0) row_start[N] = E;
    __syncthreads();
    int m = end - base;
    if (m <= BCAP) {
        for (int i = base + t; i < end; i += 256) {
            unsigned w = bucketed[i];
            int r = atomicAdd(&cnt[w >> 24], 1);
            srt[r] = (int)(w & 0xFFFFFFu);
        }
        __syncthreads();
        for (int idx = t; idx < m; idx += 256)
            csr_src[base + idx] = srt[idx];
    } else {
        // fallback: scattered writes (statistically unreachable)
        for (int i = base + t; i < end; i += 256) {
            unsigned w = bucketed[i];
            int pos = base + atomicAdd(&cnt[w >> 24], 1);
            csr_src[pos] = (int)(w & 0xFFFFFFu);
        }
    }
}

// ---- fp32-input GEMM (layer 1): H = fp16((X@W) * dis[row]), 8 outs/thread
template <int K, int M>
__global__ void k_gemm_f(const float* __restrict__ X, const float* __restrict__ W,
                         const float* __restrict__ dis, _Float16* __restrict__ H, int n) {
    constexpr int TPR = M / 8;
    constexpr int ROWS = 256 / TPR;
    constexpr int KP = K + 1;
    __shared__ float Ws[K * M];
    __shared__ float Xs[ROWS * KP];
    int tid = threadIdx.x;
    for (int idx = tid; idx < K * M / 4; idx += 256)
        ((float4*)Ws)[idx] = ((const float4*)W)[idx];
    int row0 = blockIdx.x * ROWS;
    for (int idx = tid; idx < ROWS * (K / 4); idx += 256) {
        int r = idx / (K / 4), kq = idx % (K / 4);
        int row = row0 + r;
        float4 vv = (row < n) ? ((const float4*)X)[(size_t)row * (K / 4) + kq]
                              : make_float4(0.f, 0.f, 0.f, 0.f);
        Xs[r * KP + kq * 4 + 0] = vv.x;
        Xs[r * KP + kq * 4 + 1] = vv.y;
        Xs[r * KP + kq * 4 + 2] = vv.z;
        Xs[r * KP + kq * 4 + 3] = vv.w;
    }
    __syncthreads();
    int r = tid / TPR, c0 = (tid % TPR) * 8;
    int row = row0 + r;
    if (row >= n) return;
    float4 a0 = make_float4(0.f, 0.f, 0.f, 0.f);
    float4 a1 = make_float4(0.f, 0.f, 0.f, 0.f);
#pragma unroll
    for (int k = 0; k < K; ++k) {
        float xv = Xs[r * KP + k];
        float4 w0 = ((const float4*)Ws)[(k * M + c0) / 4];
        float4 w1 = ((const float4*)Ws)[(k * M + c0) / 4 + 1];
        a0.x = fmaf(xv, w0.x, a0.x);
        a0.y = fmaf(xv, w0.y, a0.y);
        a0.z = fmaf(xv, w0.z, a0.z);
        a0.w = fmaf(xv, w0.w, a0.w);
        a1.x = fmaf(xv, w1.x, a1.x);
        a1.y = fmaf(xv, w1.y, a1.y);
        a1.z = fmaf(xv, w1.z, a1.z);
        a1.w = fmaf(xv, w1.w, a1.w);
    }
    float dn = dis[row];
    half8 hv;
    hv[0] = (_Float16)(a0.x * dn);
    hv[1] = (_Float16)(a0.y * dn);
    hv[2] = (_Float16)(a0.z * dn);
    hv[3] = (_Float16)(a0.w * dn);
    hv[4] = (_Float16)(a1.x * dn);
    hv[5] = (_Float16)(a1.y * dn);
    hv[6] = (_Float16)(a1.z * dn);
    hv[7] = (_Float16)(a1.w * dn);
    ((half8*)H)[(size_t)row * (M / 8) + c0 / 8] = hv;
}

// ---- FUSED: aggregate(64) [+relu] -> LDS -> GEMM(64 x MOUT) -> h' fp16.
// 32 nodes per block (4 waves x 8 nodes, lane-per-8-features, 8-edge unroll).
// W staged as fp16 in LDS, fp32 math.
template <int MOUT>
__global__ __launch_bounds__(256, 8)
void k_fused_agg_gemm(const _Float16* __restrict__ h, const float* __restrict__ dis,
                      const int* __restrict__ row_start, const int* __restrict__ csr_src,
                      const float* __restrict__ bagg, const float* __restrict__ W,
                      _Float16* __restrict__ H, int n) {
    constexpr int K = 64, KP = K + 1;
    __shared__ __align__(16) _Float16 Ws[K * MOUT];
    __shared__ float Xs[32 * KP];
    int tid = threadIdx.x;
    for (int idx = tid; idx < K * MOUT / 4; idx += 256) {
        float4 wv = ((const float4*)W)[idx];
        half4 h4;
        h4[0] = (_Float16)wv.x;
        h4[1] = (_Float16)wv.y;
        h4[2] = (_Float16)wv.z;
        h4[3] = (_Float16)wv.w;
        ((half4*)Ws)[idx] = h4;
    }

    int wave = tid >> 6, lane = tid & 63;
    int sub = lane >> 3, fl = lane & 7;
    int node0 = blockIdx.x * 32;
    int node = node0 + wave * 8 + sub;
    if (node < n) {
        const half8* h8 = (const half8*)h;
        float acc[8];
#pragma unroll
        for (int j = 0; j < 8; ++j) acc[j] = 0.f;
        int e = row_start[node], e1 = row_start[node + 1];
        for (; e + 7 < e1; e += 8) {
            int s0 = csr_src[e], s1 = csr_src[e + 1];
            int s2 = csr_src[e + 2], s3 = csr_src[e + 3];
            int s4 = csr_src[e + 4], s5 = csr_src[e + 5];
            int s6 = csr_src[e + 6], s7 = csr_src[e + 7];
            half8 v0 = h8[(size_t)s0 * 8 + fl];
            half8 v1 = h8[(size_t)s1 * 8 + fl];
            half8 v2 = h8[(size_t)s2 * 8 + fl];
            half8 v3 = h8[(size_t)s3 * 8 + fl];
            half8 v4 = h8[(size_t)s4 * 8 + fl];
            half8 v5 = h8[(size_t)s5 * 8 + fl];
            half8 v6 = h8[(size_t)s6 * 8 + fl];
            half8 v7 = h8[(size_t)s7 * 8 + fl];
#pragma unroll
            for (int j = 0; j < 8; ++j)
                acc[j] += (((float)v0[j] + (float)v1[j]) + ((float)v2[j] + (float)v3[j])) +
                          (((float)v4[j] + (float)v5[j]) + ((float)v6[j] + (float)v7[j]));
        }
        for (; e + 3 < e1; e += 4) {
            int s0 = csr_src[e], s1 = csr_src[e + 1];
            int s2 = csr_src[e + 2], s3 = csr_src[e + 3];
            half8 v0 = h8[(size_t)s0 * 8 + fl];
            half8 v1 = h8[(size_t)s1 * 8 + fl];
            half8 v2 = h8[(size_t)s2 * 8 + fl];
            half8 v3 = h8[(size_t)s3 * 8 + fl];
#pragma unroll
            for (int j = 0; j < 8; ++j)
                acc[j] += ((float)v0[j] + (float)v1[j]) + ((float)v2[j] + (float)v3[j]);
        }
        for (; e < e1; ++e) {
            int s0 = csr_src[e];
            half8 v0 = h8[(size_t)s0 * 8 + fl];
#pragma unroll
            for (int j = 0; j < 8; ++j) acc[j] += (float)v0[j];
        }
        float dn = dis[node];
        half8 hv = h8[(size_t)node * 8 + fl];
        float4 b0 = ((const float4*)bagg)[fl * 2];
        float4 b1 = ((const float4*)bagg)[fl * 2 + 1];
        int rrow = wave * 8 + sub;
        float* xp = &Xs[rrow * KP + fl * 8];
        xp[0] = fmaxf((acc[0] + (float)hv[0]) * dn + b0.x, 0.f);
        xp[1] = fmaxf((acc[1] + (float)hv[1]) * dn + b0.y, 0.f);
        xp[2] = fmaxf((acc[2] + (float)hv[2]) * dn + b0.z, 0.f);
        xp[3] = fmaxf((acc[3] + (float)hv[3]) * dn + b0.w, 0.f);
        xp[4] = fmaxf((acc[4] + (float)hv[4]) * dn + b1.x, 0.f);
        xp[5] = fmaxf((acc[5] + (float)hv[5]) * dn + b1.y, 0.f);
        xp[6] = fmaxf((acc[6] + (float)hv[6]) * dn + b1.z, 0.f);
        xp[7] = fmaxf((acc[7] + (float)hv[7]) * dn + b1.w, 0.f);
    }
    __syncthreads();

    constexpr int TPR = 8;
    constexpr int CPT = MOUT / TPR;   // 8 (MOUT=64) or 4 (MOUT=32)
    int r = tid / TPR, c0 = (tid % TPR) * CPT;
    int row = node0 + r;
    if (row >= n) return;
    float4 a0 = make_float4(0.f, 0.f, 0.f, 0.f);
    float4 a1 = make_float4(0.f, 0.f, 0.f, 0.f);
#pragma unroll
    for (int k = 0; k < K; ++k) {
        float xv = Xs[r * KP + k];
        if constexpr (CPT == 8) {
            half8 w = ((const half8*)Ws)[(k * MOUT + c0) / 8];
            a0.x = fmaf(xv, (float)w[0], a0.x);
            a0.y = fmaf(xv, (float)w[1], a0.y);
            a0.z = fmaf(xv, (float)w[2], a0.z);
            a0.w = fmaf(xv, (float)w[3], a0.w);
            a1.x = fmaf(xv, (float)w[4], a1.x);
            a1.y = fmaf(xv, (float)w[5], a1.y);
            a1.z = fmaf(xv, (float)w[6], a1.z);
            a1.w = fmaf(xv, (float)w[7], a1.w);
        } else {
            half4 w = ((const half4*)Ws)[(k * MOUT + c0) / 4];
            a0.x = fmaf(xv, (float)w[0], a0.x);
            a0.y = fmaf(xv, (float)w[1], a0.y);
            a0.z = fmaf(xv, (float)w[2], a0.z);
            a0.w = fmaf(xv, (float)w[3], a0.w);
        }
    }
    float dn = dis[row];
    if constexpr (CPT == 8) {
        half8 hv;
        hv[0] = (_Float16)(a0.x * dn);
        hv[1] = (_Float16)(a0.y * dn);
        hv[2] = (_Float16)(a0.z * dn);
        hv[3] = (_Float16)(a0.w * dn);
        hv[4] = (_Float16)(a1.x * dn);
        hv[5] = (_Float16)(a1.y * dn);
        hv[6] = (_Float16)(a1.z * dn);
        hv[7] = (_Float16)(a1.w * dn);
        ((half8*)H)[(size_t)row * (MOUT / 8) + c0 / 8] = hv;
    } else {
        half4 hv;
        hv[0] = (_Float16)(a0.x * dn);
        hv[1] = (_Float16)(a0.y * dn);
        hv[2] = (_Float16)(a0.z * dn);
        hv[3] = (_Float16)(a0.w * dn);
        ((half4*)H)[(size_t)row * (MOUT / 4) + c0 / 4] = hv;
    }
}

// ---- final aggregate: M=32, fp32 out, no relu.
__global__ __launch_bounds__(256, 8)
void k_aggregate32(const _Float16* __restrict__ h, const float* __restrict__ dis,
                   const int* __restrict__ row_start, const int* __restrict__ csr_src,
                   const float* __restrict__ b, float* __restrict__ out, int n) {
    constexpr int LPN = 4, NPW = 16;
    int gtid = blockIdx.x * blockDim.x + threadIdx.x;
    int wave = gtid >> 6;
    int lane = threadIdx.x & 63;
    int sub = lane / LPN, fl = lane % LPN;
    int node = wave * NPW + sub;
    if (node >= n) return;
    const half8* h8 = (const half8*)h;
    float acc[8];
#pragma unroll
    for (int j = 0; j < 8; ++j) acc[j] = 0.f;
    int e = row_start[node], e1 = row_start[node + 1];
    for (; e + 7 < e1; e += 8) {
        int s0 = csr_src[e], s1 = csr_src[e + 1];
        int s2 = csr_src[e + 2], s3 = csr_src[e + 3];
        int s4 = csr_src[e + 4], s5 = csr_src[e + 5];
        int s6 = csr_src[e + 6], s7 = csr_src[e + 7];
        half8 v0 = h8[(size_t)s0 * LPN + fl];
        half8 v1 = h8[(size_t)s1 * LPN + fl];
        half8 v2 = h8[(size_t)s2 * LPN + fl];
        half8 v3 = h8[(size_t)s3 * LPN + fl];
        half8 v4 = h8[(size_t)s4 * LPN + fl];
        half8 v5 = h8[(size_t)s5 * LPN + fl];
        half8 v6 = h8[(size_t)s6 * LPN + fl];
        half8 v7 = h8[(size_t)s7 * LPN + fl];
#pragma unroll
        for (int j = 0; j < 8; ++j)
            acc[j] += (((float)v0[j] + (float)v1[j]) + ((float)v2[j] + (float)v3[j])) +
                      (((float)v4[j] + (float)v5[j]) + ((float)v6[j] + (float)v7[j]));
    }
    for (; e + 3 < e1; e += 4) {
        int s0 = csr_src[e], s1 = csr_src[e + 1];
        int s2 = csr_src[e + 2], s3 = csr_src[e + 3];
        half8 v0 = h8[(size_t)s0 * LPN + fl];
        half8 v1 = h8[(size_t)s1 * LPN + fl];
        half8 v2 = h8[(size_t)s2 * LPN + fl];
        half8 v3 = h8[(size_t)s3 * LPN + fl];
#pragma unroll
        for (int j = 0; j < 8; ++j)
            acc[j] += ((float)v0[j] + (float)v1[j]) + ((float)v2[j] + (float)v3[j]);
    }
    for (; e < e1; ++e) {
        int s0 = csr_src[e];
        half8 v0 = h8[(size_t)s0 * LPN + fl];
#pragma unroll
        for (int j = 0; j < 8; ++j) acc[j] += (float)v0[j];
    }
    float dn = dis[node];
    half8 hv = h8[(size_t)node * LPN + fl];
    float4 b0 = ((const float4*)b)[fl * 2];
    float4 b1 = ((const float4*)b)[fl * 2 + 1];
    float4* op = (float4*)(out + ((size_t)node * LPN + fl) * 8);
    op[0] = make_float4((acc[0] + (float)hv[0]) * dn + b0.x,
                        (acc[1] + (float)hv[1]) * dn + b0.y,
                        (acc[2] + (float)hv[2]) * dn + b0.z,
                        (acc[3] + (float)hv[3]) * dn + b0.w);
    op[1] = make_float4((acc[4] + (float)hv[4]) * dn + b1.x,
                        (acc[5] + (float)hv[5]) * dn + b1.y,
                        (acc[6] + (float)hv[6]) * dn + b1.z,
                        (acc[7] + (float)hv[7]) * dn + b1.w);
}

extern "C" void kernel_launch(void* const* d_in, const int* in_sizes, int n_in,
                              void* d_out, int out_size, void* d_ws, size_t ws_size,
                              hipStream_t stream) {
    const float* x   = (const float*)d_in[0];
    const int*   ei  = (const int*)d_in[1];
    const float* W1  = (const float*)d_in[2];
    const float* b1  = (const float*)d_in[3];
    const float* W2  = (const float*)d_in[4];
    const float* b2  = (const float*)d_in[5];
    const float* W3  = (const float*)d_in[6];
    const float* b3  = (const float*)d_in[7];
    float* out = (float*)d_out;

    const int N = in_sizes[0] / 64;
    const int E = in_sizes[1] / 2;
    const int* src = ei;
    const int* dst = ei + E;

    const int NBK = cdiv(N, 128);           // 782 buckets of 128 nodes
    const int NBA = cdiv(E, ACHUNK);        // 782 chunks
    const int nmat = NBK * NBA;             // ~611K scan elements
    const int nb = cdiv(nmat, SCAN_CHUNK);  // ~598 <= 1024

    // workspace layout
    const size_t Np = (size_t)((N + 63) / 64) * 64;
    char* p = (char*)d_ws;
    int*      counts_t = (int*)p;      p += (size_t)nmat * sizeof(int);
    int*      offsets  = (int*)p;      p += (size_t)nmat * sizeof(int);
    int*      bsum     = (int*)p;      p += 1024 * sizeof(int);
    int*      row_start= (int*)p;      p += (Np + 64) * sizeof(int);
    float*    dis      = (float*)p;    p += Np * sizeof(float);
    unsigned* bucketed = (unsigned*)p; p += (size_t)E * sizeof(unsigned);
    int*      csr_src  = (int*)p;      p += (size_t)E * sizeof(int);
    _Float16* bufA     = (_Float16*)p; p += Np * 64 * sizeof(_Float16);
    _Float16* bufB     = (_Float16*)p; p += Np * 64 * sizeof(_Float16);
    (void)ws_size;

    const int B = 256;

    // ---- CSR build: LDS counting sort, no global atomics ----
    k_bucket_hist<<<NBA, B, 0, stream>>>(dst, counts_t, NBK, NBA, E);
    k_scan_partial<<<nb, B, 0, stream>>>(counts_t, bsum, nmat);
    k_scan_final<<<nb, B, 0, stream>>>(counts_t, bsum, offsets, nb, nmat);
    k_bucket_scatter<<<NBA, B, 0, stream>>>(src, dst, offsets, bucketed, NBK, NBA, E);
    k_bucket_build<<<NBK, B, 0, stream>>>(bucketed, offsets, csr_src, row_start, dis,
                                          NBK, NBA, N, E);

    // ---- layer 1 gemm: x(64) @ W1 -> h1 (bufA) ----
    k_gemm_f<64, 64><<<cdiv(N, 32), B, 0, stream>>>(x, W1, dis, bufA, N);
    // ---- fused: agg(h1)+relu -> gemm W2 -> h2 (bufB) ----
    k_fused_agg_gemm<64><<<cdiv(N, 32), B, 0, stream>>>(
        bufA, dis, row_start, csr_src, b1, W2, bufB, N);
    // ---- fused: agg(h2)+relu -> gemm W3 -> h3 (bufA, 32-dim) ----
    k_fused_agg_gemm<32><<<cdiv(N, 32), B, 0, stream>>>(
        bufB, dis, row_start, csr_src, b2, W3, bufA, N);
    // ---- final aggregate: agg(h3) + b3 -> out (fp32) ----
    k_aggregate32<<<cdiv(cdiv(N, 16) * 64, B), B, 0, stream>>>(
        bufA, dis, row_start, csr_src, b3, out, N);
}